// Round 7
// baseline (274.782 us; speedup 1.0000x reference)
//
#include <hip/hip_runtime.h>
#include <math.h>

#define B_ 2
#define S_ 2048
#define D_ 1024
#define H_ 16
#define DK_ 64

typedef __attribute__((ext_vector_type(8))) short bf16x8;
typedef __attribute__((ext_vector_type(4))) float f32x4;

#define MFMA16(a, b, c) __builtin_amdgcn_mfma_f32_16x16x32_bf16((a), (b), (c), 0, 0, 0)

#define ASYNC16(g, l)                                                          \
    __builtin_amdgcn_global_load_lds(                                          \
        (const __attribute__((address_space(1))) void*)(g),                    \
        (__attribute__((address_space(3))) void*)(l), 16, 0, 0)

#define LOG2E 1.4426950408889634f

__device__ __forceinline__ unsigned short f2bf(float x) {
    unsigned int u = __float_as_uint(x);
    unsigned int r = (u + 0x7fffu + ((u >> 16) & 1u)) >> 16;
    return (unsigned short)r;
}

// ---------------------------------------------------------------------------
// pack: fp32 -> bf16 (plain), z selects tensor.
// ---------------------------------------------------------------------------
__global__ __launch_bounds__(256)
void pack_all(const float* __restrict__ q, const float* __restrict__ k,
              const float* __restrict__ v, const float* __restrict__ wq,
              const float* __restrict__ wk, const float* __restrict__ wv,
              const float* __restrict__ wo, unsigned short* __restrict__ ws0)
{
    const int z = blockIdx.z;
    const size_t IN = 4194304, WT = 1048576;
    const float* in;
    unsigned short* dst;
    int n;
    switch (z) {
        case 0: in = q;  dst = ws0;            n = (int)IN; break;
        case 1: in = k;  dst = ws0 + IN;       n = (int)IN; break;
        case 2: in = v;  dst = ws0 + 2*IN;     n = (int)IN; break;
        case 3: in = wq; dst = ws0 + 3*IN;          n = (int)WT; break;
        case 4: in = wk; dst = ws0 + 3*IN + WT;     n = (int)WT; break;
        case 5: in = wv; dst = ws0 + 3*IN + 2*WT;   n = (int)WT; break;
        default:in = wo; dst = ws0 + 3*IN + 3*WT;   n = (int)WT; break;
    }
    const int n4 = n >> 2;
    const int stride = gridDim.x * blockDim.x;
    for (int i = blockIdx.x * blockDim.x + threadIdx.x; i < n4; i += stride) {
        float4 x = ((const float4*)in)[i];
        ushort4 hv;
        hv.x = f2bf(x.x); hv.y = f2bf(x.y); hv.z = f2bf(x.z); hv.w = f2bf(x.w);
        ((ushort4*)dst)[i] = hv;
    }
}

// ---------------------------------------------------------------------------
// bf16 GEMM core, 2-PHASE double-buffered (T3 minimum recipe):
//   prologue: STAGE(buf0, k=0); sync
//   iter k:   STAGE(buf^1, k+1)  [issued, not drained]
//             compute(buf[k&1])  [ds_read + MFMA, covers stage latency]
//             __syncthreads()    [vmcnt(0) drain lands AFTER full compute]
// One barrier per K-step, stage overlapped with compute.
// Tile 128x64, BK=64, 256 thr / 4 waves (wave-tile 64x32, acc[4][2]).
// LDS = 2*16K(A) + 2*8K(B) = 48 KB -> 3 blocks/CU.
// ---------------------------------------------------------------------------
__device__ __forceinline__ void gemm_core2ph(
    const unsigned short* __restrict__ A, const unsigned short* __restrict__ B,
    unsigned short (*As)[128 * 64], unsigned short (*Bs)[64 * 64],
    int m0, int n0, f32x4 (&acc)[4][2])
{
    const int tid  = threadIdx.x;
    const int w    = tid >> 6;
    const int lane = tid & 63;
    const int rA   = lane & 15;
    const int quad = lane >> 4;
    const int wm   = (w & 1) * 64;
    const int wn   = (w >> 1) * 32;

    const int rowc = tid >> 3;               // 0..31 (8 chunks per 64-col row)
    const int gc   = (tid & 7) ^ (rowc & 7); // XOR-8 pre-swizzled source chunk

#define STA(buf, k0) do {                                                       \
        _Pragma("unroll")                                                       \
        for (int i_ = 0; i_ < 4; ++i_)                                          \
            ASYNC16(A + (size_t)(m0 + i_ * 32 + rowc) * 1024 + (k0) + gc * 8,   \
                    &As[buf][(size_t)(i_ * 256 + w * 64) * 8]);                 \
    } while (0)
#define STB(buf, k0) do {                                                       \
        _Pragma("unroll")                                                       \
        for (int i_ = 0; i_ < 2; ++i_)                                          \
            ASYNC16(B + (size_t)(n0 + i_ * 32 + rowc) * 1024 + (k0) + gc * 8,   \
                    &Bs[buf][(size_t)(i_ * 256 + w * 64) * 8]);                 \
    } while (0)

    STA(0, 0);
    STB(0, 0);
    __syncthreads();                          // stage(0) complete

#pragma unroll 1
    for (int k = 0; k < 16; ++k) {
        const int cur = k & 1;
        if (k < 15) {                         // stage k+1 into other buffer
            STA(cur ^ 1, (k + 1) * 64);
            STB(cur ^ 1, (k + 1) * 64);
        }
#pragma unroll
        for (int ks = 0; ks < 2; ++ks) {
            bf16x8 a[4], bb[2];
#pragma unroll
            for (int mt = 0; mt < 4; ++mt) {
                const int row = wm + mt * 16 + rA;
                a[mt] = *(const bf16x8*)
                    &As[cur][row * 64 + (((ks * 4 + quad) ^ (row & 7)) * 8)];
            }
#pragma unroll
            for (int nt = 0; nt < 2; ++nt) {
                const int row = wn + nt * 16 + rA;
                bb[nt] = *(const bf16x8*)
                    &Bs[cur][row * 64 + (((ks * 4 + quad) ^ (row & 7)) * 8)];
            }
#pragma unroll
            for (int mt = 0; mt < 4; ++mt)
#pragma unroll
                for (int nt = 0; nt < 2; ++nt)
                    acc[mt][nt] = MFMA16(a[mt], bb[nt], acc[mt][nt]);
        }
        __syncthreads();                      // drain stage(k+1); reads done
    }
#undef STA
#undef STB
}

// XCD-aware swizzle (T1): physical bid%8 == XCD (round-robin dispatch), so
// swz = (bid&7)*(nwg/8) + bid>>3 gives each XCD a contiguous logical chunk:
// XCD k owns logicals [64k,64k+64) = 4 consecutive m-panels x all 16 n-cols.
// A-panel (256 KB) then re-reads 15x from that XCD's L2; the 2 MB weight
// matrix stays L2-resident across the 4 panels.  nwg=512, bijective.
__device__ __forceinline__ void swz512(int& m0, int& n0) {
    const int bid = (int)(blockIdx.x + (blockIdx.y << 4));   // gridDim.x == 16
    const int swz = (bid & 7) * 64 + (bid >> 3);
    m0 = (swz >> 4) * 128;
    n0 = (swz & 15) * 64;
}

// QKV projection, ONE z per dispatch (measurement round: per-z durations and
// counters become visible in the top-5 table).  q,k -> (b,h,s,dk);
// v -> (b,h,dk,s).  q pre-scaled by 0.125*log2(e).
__global__ __launch_bounds__(256, 3)
void gemm_qkv(const unsigned short* __restrict__ ws0,
              const float* __restrict__ bq, const float* __restrict__ bk,
              const float* __restrict__ bv,
              unsigned short* __restrict__ qbuf, unsigned short* __restrict__ kbuf,
              unsigned short* __restrict__ vtbuf, const int z)
{
    __shared__ unsigned short As[2][128 * 64];
    __shared__ unsigned short Bs[2][64 * 64];
    const size_t IN = 4194304, WT = 1048576;
    const unsigned short* Ap = ws0 + (size_t)z * IN;
    const unsigned short* Bp = ws0 + 3 * IN + (size_t)z * WT;
    const float* bias = (z == 0) ? bq : (z == 1) ? bk : bv;
    unsigned short* dst = (z == 0) ? qbuf : (z == 1) ? kbuf : vtbuf;

    int m0, n0;
    swz512(m0, n0);
    f32x4 acc[4][2] = {};
    gemm_core2ph(Ap, Bp, As, Bs, m0, n0, acc);

    const int tid = threadIdx.x, w = tid >> 6, lane = tid & 63;
    const int quad = lane >> 4, col = lane & 15;
    const int wm = (w & 1) * 64, wn = (w >> 1) * 32;
    const float qscale = (z == 0) ? (0.125f * LOG2E) : 1.0f;
#pragma unroll
    for (int mt = 0; mt < 4; ++mt)
#pragma unroll
        for (int nt = 0; nt < 2; ++nt) {
            f32x4 v = acc[mt][nt];
#pragma unroll
            for (int r = 0; r < 4; ++r) {
                const int m = m0 + wm + mt * 16 + quad * 4 + r;
                const int n = n0 + wn + nt * 16 + col;
                const float val = (v[r] + bias[n]) * qscale;
                const int bb = m >> 11, ss = m & 2047;
                const int hh = n >> 6, dd = n & 63;
                if (z == 2)
                    dst[((size_t)(bb * 16 + hh) * 64 + dd) * 2048 + ss] = f2bf(val);
                else
                    dst[((size_t)(bb * 16 + hh) * 2048 + ss) * 64 + dd] = f2bf(val);
            }
        }
}

// Output projection: out = ctx(bf16) . Wo^T + bo, fp32 out.
__global__ __launch_bounds__(256, 3)
void gemm_out(const unsigned short* __restrict__ Actx,
              const unsigned short* __restrict__ Bwo,
              const float* __restrict__ bias, float* __restrict__ out)
{
    __shared__ unsigned short As[2][128 * 64];
    __shared__ unsigned short Bs[2][64 * 64];
    int m0, n0;
    swz512(m0, n0);
    f32x4 acc[4][2] = {};
    gemm_core2ph(Actx, Bwo, As, Bs, m0, n0, acc);

    const int tid = threadIdx.x, w = tid >> 6, lane = tid & 63;
    const int quad = lane >> 4, col = lane & 15;
    const int wm = (w & 1) * 64, wn = (w >> 1) * 32;
#pragma unroll
    for (int mt = 0; mt < 4; ++mt)
#pragma unroll
        for (int nt = 0; nt < 2; ++nt) {
            f32x4 v = acc[mt][nt];
#pragma unroll
            for (int r = 0; r < 4; ++r) {
                const int m = m0 + wm + mt * 16 + quad * 4 + r;
                const int n = n0 + wn + nt * 16 + col;
                out[(size_t)m * 1024 + n] = v[r] + bias[n];
            }
        }
}

// ---------------------------------------------------------------------------
// Flash attention (round-2 version, verified 79.6us): 256 thr = 4 waves,
// each wave owns 32 q-rows (mt=2).  K/V triple-buffered, staged 2 tiles
// ahead; posr 1 tile ahead with PV+QK as latency cover; per-tile barrier is
// raw s_barrier + lgkmcnt(0) only (no vmcnt drain).  Safety: posr loads are
// pinned (sched_barrier) after the ASYNC16s, so the compiler's wait on pr at
// softmax(t) implies (in-order vmcnt retirement) all earlier stages
// completed; buffer WAR is separated by a barrier with lgkm drained.  Ps
// rows are wave-private, so one barrier per tile suffices.
// ---------------------------------------------------------------------------
__global__ __launch_bounds__(256, 2)
void attn_mfma(const unsigned short* __restrict__ qbuf,
               const unsigned short* __restrict__ kbuf,
               const unsigned short* __restrict__ vtbuf,
               const float* __restrict__ posr, const int* __restrict__ mask,
               unsigned short* __restrict__ ctxb)
{
    __shared__ unsigned short Ks[3][64 * 64];
    __shared__ unsigned short Vts[3][64 * 64];
    __shared__ unsigned short Ps[128 * 64];

    const int tid  = threadIdx.x;
    const int w    = tid >> 6;          // wave 0..3
    const int lane = tid & 63;
    const int quad = lane >> 4;
    const int col  = lane & 15;
    const int q0   = blockIdx.x * 128;
    const int h    = blockIdx.y;
    const int b    = blockIdx.z;
    const int wq   = w * 32;            // 32 q-rows per wave

    const size_t headoff = (size_t)(b * 16 + h) * 2048 * 64;
    const unsigned short* Qh  = qbuf + headoff + (size_t)q0 * 64;
    const unsigned short* Kh  = kbuf + headoff;
    const unsigned short* Vth = vtbuf + headoff;

    // staging geometry: 2 chunks per thread per tensor per tile
    const int c0 = tid;
    const int c1 = 256 + tid;
    const int r0 = c0 >> 3, g0 = (c0 & 7) ^ (r0 & 7);
    const int r1 = c1 >> 3, g1 = (c1 & 7) ^ (r1 & 7);

#define STAGE(bufidx, kt) do {                                                  \
        ASYNC16(Kh + (size_t)((kt) * 64 + r0) * 64 + g0 * 8,                    \
                &Ks[bufidx][(size_t)(w * 64) * 8]);                             \
        ASYNC16(Kh + (size_t)((kt) * 64 + r1) * 64 + g1 * 8,                    \
                &Ks[bufidx][(size_t)(256 + w * 64) * 8]);                       \
        ASYNC16(Vth + (size_t)r0 * 2048 + (kt) * 64 + g0 * 8,                   \
                &Vts[bufidx][(size_t)(w * 64) * 8]);                            \
        ASYNC16(Vth + (size_t)r1 * 2048 + (kt) * 64 + g1 * 8,                   \
                &Vts[bufidx][(size_t)(256 + w * 64) * 8]);                      \
    } while (0)

    // Q fragments (A-layout: m=col, k=ks*32+quad*8+j), 2 m-tiles x 2 ks
    bf16x8 qf[2][2];
#pragma unroll
    for (int mt = 0; mt < 2; ++mt)
#pragma unroll
        for (int ks = 0; ks < 2; ++ks)
            qf[mt][ks] = *(const bf16x8*)
                &Qh[(size_t)(wq + mt * 16 + col) * 64 + ks * 32 + quad * 8];

    // posr row pointers (8 rows per lane: mt x r)
    const float* prq[2][4];
#pragma unroll
    for (int mt = 0; mt < 2; ++mt)
#pragma unroll
        for (int r = 0; r < 4; ++r)
            prq[mt][r] = posr +
                ((size_t)b * 2048 + (q0 + wq + mt * 16 + quad * 4 + r)) * 2048;
    const int* mrow = mask + (size_t)b * 2048;

    // stage tiles 0,1
    STAGE(0, 0);
    STAGE(1, 1);

    // posr/mask for tile 0
    float pr[2][4][4];
    int   mk[4];
#pragma unroll
    for (int mt = 0; mt < 2; ++mt)
#pragma unroll
        for (int r = 0; r < 4; ++r)
#pragma unroll
            for (int nt = 0; nt < 4; ++nt)
                pr[mt][r][nt] = prq[mt][r][nt * 16 + col];
#pragma unroll
    for (int nt = 0; nt < 4; ++nt) mk[nt] = mrow[nt * 16 + col];

    f32x4 sc[2][4];
    f32x4 O[2][4] = {};
    float lsum[2][4] = {{0.f, 0.f, 0.f, 0.f}, {0.f, 0.f, 0.f, 0.f}};

    __syncthreads();                    // tiles 0,1 staged (full drain, once)

    // QK(0) from buffer 0
#pragma unroll
    for (int mt = 0; mt < 2; ++mt)
#pragma unroll
        for (int nt = 0; nt < 4; ++nt) sc[mt][nt] = (f32x4){0.f, 0.f, 0.f, 0.f};
#pragma unroll
    for (int nt = 0; nt < 4; ++nt)
#pragma unroll
        for (int ks = 0; ks < 2; ++ks) {
            const bf16x8 bk = *(const bf16x8*)
                &Ks[0][(nt * 16 + col) * 64 + (((ks * 4 + quad) ^ (col & 7)) * 8)];
#pragma unroll
            for (int mt = 0; mt < 2; ++mt)
                sc[mt][nt] = MFMA16(qf[mt][ks], bk, sc[mt][nt]);
        }

    int bb = 0, b1 = 1, b2 = 2;
#pragma unroll 1
    for (int t = 0; t < 32; ++t) {
        // ---- softmax(t): p = exp2(sc + pr*log2e); truncate-pack; l exact ----
#pragma unroll
        for (int mt = 0; mt < 2; ++mt)
#pragma unroll
            for (int r = 0; r < 4; ++r) {
                const int rowW = wq + mt * 16 + quad * 4 + r;
                const int rsw  = rowW & 7;
#pragma unroll
                for (int nt = 0; nt < 4; ++nt) {
                    const float e = __builtin_amdgcn_exp2f(
                        fmaf(pr[mt][r][nt], LOG2E, sc[mt][nt][r]));
                    unsigned int u = __float_as_uint(e) & 0xffff0000u;
                    u = mk[nt] ? u : 0u;
                    lsum[mt][r] += __uint_as_float(u);
                    const int kk = nt * 16 + col;
                    Ps[rowW * 64 + (((kk >> 3) ^ rsw) * 8) + (kk & 7)] =
                        (unsigned short)(u >> 16);
                }
            }

        // barrier: publish Ps(t); stage(t+1) already covered by softmax's
        // wait on pr(t) (posr loads pinned after stages).  No vmcnt drain.
        __builtin_amdgcn_sched_barrier(0);
        asm volatile("s_waitcnt lgkmcnt(0)" ::: "memory");
        __builtin_amdgcn_s_barrier();
        __builtin_amdgcn_sched_barrier(0);

        // stage t+2 into b2 (its previous readers retired before last barrier)
        if (t < 30) STAGE(b2, t + 2);
        __builtin_amdgcn_sched_barrier(0);   // pin: stages BEFORE posr loads

        // posr/mask prefetch for t+1 (cover = PV + QK below)
        if (t < 31) {
            const int kn = (t + 1) * 64;
#pragma unroll
            for (int mt = 0; mt < 2; ++mt)
#pragma unroll
                for (int r = 0; r < 4; ++r)
#pragma unroll
                    for (int nt = 0; nt < 4; ++nt)
                        pr[mt][r][nt] = prq[mt][r][kn + nt * 16 + col];
#pragma unroll
            for (int nt = 0; nt < 4; ++nt) mk[nt] = mrow[kn + nt * 16 + col];
        }

        // ---- PV(t): O += P.V from buffer bb ----
#pragma unroll
        for (int ks = 0; ks < 2; ++ks) {
            bf16x8 pa[2];
#pragma unroll
            for (int mt = 0; mt < 2; ++mt)
                pa[mt] = *(const bf16x8*)
                    &Ps[(wq + mt * 16 + col) * 64 + (((ks * 4 + quad) ^ (col & 7)) * 8)];
#pragma unroll
            for (int nt = 0; nt < 4; ++nt) {
                const bf16x8 vb = *(const bf16x8*)
                    &Vts[bb][(nt * 16 + col) * 64 + (((ks * 4 + quad) ^ (col & 7)) * 8)];
#pragma unroll
                for (int mt = 0; mt < 2; ++mt)
                    O[mt][nt] = MFMA16(pa[mt], vb, O[mt][nt]);
            }
        }

        // ---- QK(t+1) from buffer b1 ----
        if (t < 31) {
#pragma unroll
            for (int mt = 0; mt < 2; ++mt)
#pragma unroll
                for (int nt = 0; nt < 4; ++nt)
                    sc[mt][nt] = (f32x4){0.f, 0.f, 0.f, 0.f};
#pragma unroll
            for (int nt = 0; nt < 4; ++nt)
#pragma unroll
                for (int ks = 0; ks < 2; ++ks) {
                    const bf16x8 bk = *(const bf16x8*)
                        &Ks[b1][(nt * 16 + col) * 64 + (((ks * 4 + quad) ^ (col & 7)) * 8)];
#pragma unroll
                    for (int mt = 0; mt < 2; ++mt)
                        sc[mt][nt] = MFMA16(qf[mt][ks], bk, sc[mt][nt]);
                }
        }
        const int tmp = bb; bb = b1; b1 = b2; b2 = tmp;
    }

    // ---- reduce l across the 16 cols (rows are wave-private) ----
#pragma unroll
    for (int mt = 0; mt < 2; ++mt)
#pragma unroll
        for (int r = 0; r < 4; ++r) {
#pragma unroll
            for (int o = 1; o < 16; o <<= 1)
                lsum[mt][r] += __shfl_xor(lsum[mt][r], o);
        }

    // ---- epilogue: ctx = O / l (bf16) ----
#pragma unroll
    for (int mt = 0; mt < 2; ++mt)
#pragma unroll
        for (int r = 0; r < 4; ++r) {
            const float inv = 1.f / lsum[mt][r];
            const int rowW = wq + mt * 16 + quad * 4 + r;
            const size_t rowoff =
                ((size_t)b * 2048 + (q0 + rowW)) * 1024 + h * 64;
#pragma unroll
            for (int nt = 0; nt < 4; ++nt)
                ctxb[rowoff + nt * 16 + col] = f2bf(O[mt][nt][r] * inv);
        }
#undef STAGE
}

// ---------------------------------------------------------------------------
extern "C" void kernel_launch(void* const* d_in, const int* in_sizes, int n_in,
                              void* d_out, int out_size, void* d_ws, size_t ws_size,
                              hipStream_t stream) {
    const float* query = (const float*)d_in[0];
    const float* key   = (const float*)d_in[1];
    const float* value = (const float*)d_in[2];
    const int*   mask  = (const int*)  d_in[3];
    const float* posr  = (const float*)d_in[4];
    const float* Wq    = (const float*)d_in[5];
    const float* bq    = (const float*)d_in[6];
    const float* Wk    = (const float*)d_in[7];
    const float* bk    = (const float*)d_in[8];
    const float* Wv    = (const float*)d_in[9];
    const float* bv    = (const float*)d_in[10];
    const float* Wo    = (const float*)d_in[11];
    const float* bo    = (const float*)d_in[12];
    float* out = (float*)d_out;

    unsigned short* ws0   = (unsigned short*)d_ws;
    const size_t IN = 4194304, WT = 1048576;
    unsigned short* qbuf  = ws0 + 4 * IN;
    unsigned short* kbuf  = ws0 + 5 * IN;
    unsigned short* vtbuf = ws0 + 6 * IN;
    unsigned short* ctxb  = ws0 + 7 * IN;
    const unsigned short* wob = ws0 + 3 * IN + 3 * WT;

    pack_all<<<dim3(512, 1, 7), 256, 0, stream>>>(query, key, value, Wq, Wk, Wv, Wo, ws0);

    // measurement round: one dispatch per z so per-GEMM counters surface
    gemm_qkv<<<dim3(16, 32), 256, 0, stream>>>(ws0, bq, bk, bv, qbuf, kbuf, vtbuf, 0);
    gemm_qkv<<<dim3(16, 32), 256, 0, stream>>>(ws0, bq, bk, bv, qbuf, kbuf, vtbuf, 1);
    gemm_qkv<<<dim3(16, 32), 256, 0, stream>>>(ws0, bq, bk, bv, qbuf, kbuf, vtbuf, 2);

    attn_mfma<<<dim3(16, 16, 2), 256, 0, stream>>>(qbuf, kbuf, vtbuf, posr, mask, ctxb);

    gemm_out<<<dim3(16, 32), 256, 0, stream>>>(ctxb, wob, bo, out);
}

// Round 8
// 259.162 us; speedup vs baseline: 1.0603x; 1.0603x over previous
//
#include <hip/hip_runtime.h>
#include <math.h>

#define B_ 2
#define S_ 2048
#define D_ 1024
#define H_ 16
#define DK_ 64

typedef __attribute__((ext_vector_type(8))) short bf16x8;
typedef __attribute__((ext_vector_type(4))) float f32x4;

#define MFMA16(a, b, c) __builtin_amdgcn_mfma_f32_16x16x32_bf16((a), (b), (c), 0, 0, 0)

#define ASYNC16(g, l)                                                          \
    __builtin_amdgcn_global_load_lds(                                          \
        (const __attribute__((address_space(1))) void*)(g),                    \
        (__attribute__((address_space(3))) void*)(l), 16, 0, 0)

#define LOG2E 1.4426950408889634f

__device__ __forceinline__ unsigned short f2bf(float x) {
    unsigned int u = __float_as_uint(x);
    unsigned int r = (u + 0x7fffu + ((u >> 16) & 1u)) >> 16;
    return (unsigned short)r;
}

// ---------------------------------------------------------------------------
// pack: fp32 -> bf16 (plain), z selects tensor.
// ---------------------------------------------------------------------------
__global__ __launch_bounds__(256)
void pack_all(const float* __restrict__ q, const float* __restrict__ k,
              const float* __restrict__ v, const float* __restrict__ wq,
              const float* __restrict__ wk, const float* __restrict__ wv,
              const float* __restrict__ wo, unsigned short* __restrict__ ws0)
{
    const int z = blockIdx.z;
    const size_t IN = 4194304, WT = 1048576;
    const float* in;
    unsigned short* dst;
    int n;
    switch (z) {
        case 0: in = q;  dst = ws0;            n = (int)IN; break;
        case 1: in = k;  dst = ws0 + IN;       n = (int)IN; break;
        case 2: in = v;  dst = ws0 + 2*IN;     n = (int)IN; break;
        case 3: in = wq; dst = ws0 + 3*IN;          n = (int)WT; break;
        case 4: in = wk; dst = ws0 + 3*IN + WT;     n = (int)WT; break;
        case 5: in = wv; dst = ws0 + 3*IN + 2*WT;   n = (int)WT; break;
        default:in = wo; dst = ws0 + 3*IN + 3*WT;   n = (int)WT; break;
    }
    const int n4 = n >> 2;
    const int stride = gridDim.x * blockDim.x;
    for (int i = blockIdx.x * blockDim.x + threadIdx.x; i < n4; i += stride) {
        float4 x = ((const float4*)in)[i];
        ushort4 hv;
        hv.x = f2bf(x.x); hv.y = f2bf(x.y); hv.z = f2bf(x.z); hv.w = f2bf(x.w);
        ((ushort4*)dst)[i] = hv;
    }
}

// ---------------------------------------------------------------------------
// bf16 GEMM core, 2-PHASE double-buffered (T3 minimum recipe):
//   prologue: STAGE(buf0, k=0); sync
//   iter k:   STAGE(buf^1, k+1)  [issued, not drained]
//             compute(buf[k&1])  [ds_read + MFMA, covers stage latency]
//             __syncthreads()    [vmcnt(0) drain lands AFTER full compute]
// One barrier per K-step, stage overlapped with compute.
// Tile 128x64, BK=64, 256 thr / 4 waves (wave-tile 64x32, acc[4][2]).
// LDS = 2*16K(A) + 2*8K(B) = 48 KB -> 3 blocks/CU.
// ---------------------------------------------------------------------------
__device__ __forceinline__ void gemm_core2ph(
    const unsigned short* __restrict__ A, const unsigned short* __restrict__ B,
    unsigned short (*As)[128 * 64], unsigned short (*Bs)[64 * 64],
    int m0, int n0, f32x4 (&acc)[4][2])
{
    const int tid  = threadIdx.x;
    const int w    = tid >> 6;
    const int lane = tid & 63;
    const int rA   = lane & 15;
    const int quad = lane >> 4;
    const int wm   = (w & 1) * 64;
    const int wn   = (w >> 1) * 32;

    const int rowc = tid >> 3;               // 0..31 (8 chunks per 64-col row)
    const int gc   = (tid & 7) ^ (rowc & 7); // XOR-8 pre-swizzled source chunk

#define STA(buf, k0) do {                                                       \
        _Pragma("unroll")                                                       \
        for (int i_ = 0; i_ < 4; ++i_)                                          \
            ASYNC16(A + (size_t)(m0 + i_ * 32 + rowc) * 1024 + (k0) + gc * 8,   \
                    &As[buf][(size_t)(i_ * 256 + w * 64) * 8]);                 \
    } while (0)
#define STB(buf, k0) do {                                                       \
        _Pragma("unroll")                                                       \
        for (int i_ = 0; i_ < 2; ++i_)                                          \
            ASYNC16(B + (size_t)(n0 + i_ * 32 + rowc) * 1024 + (k0) + gc * 8,   \
                    &Bs[buf][(size_t)(i_ * 256 + w * 64) * 8]);                 \
    } while (0)

    STA(0, 0);
    STB(0, 0);
    __syncthreads();                          // stage(0) complete

#pragma unroll 1
    for (int k = 0; k < 16; ++k) {
        const int cur = k & 1;
        if (k < 15) {                         // stage k+1 into other buffer
            STA(cur ^ 1, (k + 1) * 64);
            STB(cur ^ 1, (k + 1) * 64);
        }
#pragma unroll
        for (int ks = 0; ks < 2; ++ks) {
            bf16x8 a[4], bb[2];
#pragma unroll
            for (int mt = 0; mt < 4; ++mt) {
                const int row = wm + mt * 16 + rA;
                a[mt] = *(const bf16x8*)
                    &As[cur][row * 64 + (((ks * 4 + quad) ^ (row & 7)) * 8)];
            }
#pragma unroll
            for (int nt = 0; nt < 2; ++nt) {
                const int row = wn + nt * 16 + rA;
                bb[nt] = *(const bf16x8*)
                    &Bs[cur][row * 64 + (((ks * 4 + quad) ^ (row & 7)) * 8)];
            }
#pragma unroll
            for (int mt = 0; mt < 4; ++mt)
#pragma unroll
                for (int nt = 0; nt < 2; ++nt)
                    acc[mt][nt] = MFMA16(a[mt], bb[nt], acc[mt][nt]);
        }
        __syncthreads();                      // drain stage(k+1); reads done
    }
#undef STA
#undef STB
}

// XCD-aware swizzle (T1): physical bid%8 == XCD (round-robin dispatch), so
// swz = (bid&7)*(nwg/8) + bid>>3 gives each XCD a contiguous logical chunk:
// XCD k owns logicals [64k,64k+64) = 4 consecutive m-panels x all 16 n-cols.
// A-panel (256 KB) then re-reads 15x from that XCD's L2; the 2 MB weight
// matrix stays L2-resident across the 4 panels.  nwg=512, bijective.
__device__ __forceinline__ void swz512(int& m0, int& n0) {
    const int bid = (int)(blockIdx.x + (blockIdx.y << 4));   // gridDim.x == 16
    const int swz = (bid & 7) * 64 + (bid >> 3);
    m0 = (swz >> 4) * 128;
    n0 = (swz & 15) * 64;
}

// QKV projections.  q,k -> (b,h,s,dk); v -> (b,h,dk,s).
// q pre-scaled by 0.125*log2(e) so attention uses exp2 directly.
// z==2 (V^T) routes the output tile through LDS and stores COALESCED:
// the direct scatter (2B stores at 4KB stride, lane-adjacent dd) dirtied one
// cacheline per element = ~32x write amplification (~540 MB HBM write-back
// for a 17 MB tensor) -- the hidden ~80us sink of rounds 0-7.
__global__ __launch_bounds__(256, 3)
void gemm_qkv(const unsigned short* __restrict__ ws0,
              const float* __restrict__ bq, const float* __restrict__ bk,
              const float* __restrict__ bv,
              unsigned short* __restrict__ qbuf, unsigned short* __restrict__ kbuf,
              unsigned short* __restrict__ vtbuf)
{
    __shared__ unsigned short As[2][128 * 64];
    __shared__ unsigned short Bs[2][64 * 64];
    const size_t IN = 4194304, WT = 1048576;
    const int z = blockIdx.z;
    const unsigned short* Ap = ws0 + (size_t)z * IN;
    const unsigned short* Bp = ws0 + 3 * IN + (size_t)z * WT;
    const float* bias = (z == 0) ? bq : (z == 1) ? bk : bv;
    unsigned short* dst = (z == 0) ? qbuf : (z == 1) ? kbuf : vtbuf;

    int m0, n0;
    swz512(m0, n0);
    f32x4 acc[4][2] = {};
    gemm_core2ph(Ap, Bp, As, Bs, m0, n0, acc);

    const int tid = threadIdx.x, w = tid >> 6, lane = tid & 63;
    const int quad = lane >> 4, col = lane & 15;
    const int wm = (w & 1) * 64, wn = (w >> 1) * 32;

    if (z == 2) {
        // ---- transpose-in-LDS epilogue: coalesced V^T stores ----
        unsigned short* Ts = &As[0][0];          // 16 KB, free after core
#pragma unroll
        for (int mt = 0; mt < 4; ++mt)
#pragma unroll
            for (int nt = 0; nt < 2; ++nt) {
                const int ln  = wn + nt * 16 + col;       // d within tile 0..63
                const int lmb = wm + mt * 16 + quad * 4;  // s within tile, 4-aligned
                const float bv_ = bias[n0 + ln];
                ushort4 h;
                h.x = f2bf(acc[mt][nt][0] + bv_);
                h.y = f2bf(acc[mt][nt][1] + bv_);
                h.z = f2bf(acc[mt][nt][2] + bv_);
                h.w = f2bf(acc[mt][nt][3] + bv_);
                // XOR-swizzle the s-index by d to spread banks
                *(ushort4*)&Ts[ln * 128 + (lmb ^ ((ln & 7) << 3))] = h;
            }
        __syncthreads();
        const int d    = tid >> 2;               // V^T row within tile, 0..63
        const int cg   = (tid & 3) * 32;         // 32 s-cols per thread
        const int bb   = m0 >> 11;
        const int sb   = m0 & 2047;
        const int hh   = n0 >> 6;
        unsigned short* drow =
            dst + ((size_t)(bb * 16 + hh) * 64 + d) * 2048 + sb;
#pragma unroll
        for (int j = 0; j < 8; ++j) {
            const int c = cg + j * 4;
            ushort4 hv = *(const ushort4*)&Ts[d * 128 + (c ^ ((d & 7) << 3))];
            *(ushort4*)&drow[c] = hv;            // 8B chunks, 256B/row contiguous
        }
        return;
    }

    const float qscale = (z == 0) ? (0.125f * LOG2E) : 1.0f;
#pragma unroll
    for (int mt = 0; mt < 4; ++mt)
#pragma unroll
        for (int nt = 0; nt < 2; ++nt) {
            f32x4 v = acc[mt][nt];
#pragma unroll
            for (int r = 0; r < 4; ++r) {
                const int m = m0 + wm + mt * 16 + quad * 4 + r;
                const int n = n0 + wn + nt * 16 + col;
                const float val = (v[r] + bias[n]) * qscale;
                const int bb = m >> 11, ss = m & 2047;
                const int hh = n >> 6, dd = n & 63;
                dst[((size_t)(bb * 16 + hh) * 2048 + ss) * 64 + dd] = f2bf(val);
            }
        }
}

// Output projection: out = ctx(bf16) . Wo^T + bo, fp32 out.
__global__ __launch_bounds__(256, 3)
void gemm_out(const unsigned short* __restrict__ Actx,
              const unsigned short* __restrict__ Bwo,
              const float* __restrict__ bias, float* __restrict__ out)
{
    __shared__ unsigned short As[2][128 * 64];
    __shared__ unsigned short Bs[2][64 * 64];
    int m0, n0;
    swz512(m0, n0);
    f32x4 acc[4][2] = {};
    gemm_core2ph(Actx, Bwo, As, Bs, m0, n0, acc);

    const int tid = threadIdx.x, w = tid >> 6, lane = tid & 63;
    const int quad = lane >> 4, col = lane & 15;
    const int wm = (w & 1) * 64, wn = (w >> 1) * 32;
#pragma unroll
    for (int mt = 0; mt < 4; ++mt)
#pragma unroll
        for (int nt = 0; nt < 2; ++nt) {
            f32x4 v = acc[mt][nt];
#pragma unroll
            for (int r = 0; r < 4; ++r) {
                const int m = m0 + wm + mt * 16 + quad * 4 + r;
                const int n = n0 + wn + nt * 16 + col;
                out[(size_t)m * 1024 + n] = v[r] + bias[n];
            }
        }
}

// ---------------------------------------------------------------------------
// Flash attention (round-2 version, verified 79.6us): 256 thr = 4 waves,
// each wave owns 32 q-rows (mt=2).  K/V triple-buffered, staged 2 tiles
// ahead; posr 1 tile ahead with PV+QK as latency cover; per-tile barrier is
// raw s_barrier + lgkmcnt(0) only (no vmcnt drain).  Safety: posr loads are
// pinned (sched_barrier) after the ASYNC16s, so the compiler's wait on pr at
// softmax(t) implies (in-order vmcnt retirement) all earlier stages
// completed; buffer WAR is separated by a barrier with lgkm drained.  Ps
// rows are wave-private, so one barrier per tile suffices.
// ---------------------------------------------------------------------------
__global__ __launch_bounds__(256, 2)
void attn_mfma(const unsigned short* __restrict__ qbuf,
               const unsigned short* __restrict__ kbuf,
               const unsigned short* __restrict__ vtbuf,
               const float* __restrict__ posr, const int* __restrict__ mask,
               unsigned short* __restrict__ ctxb)
{
    __shared__ unsigned short Ks[3][64 * 64];
    __shared__ unsigned short Vts[3][64 * 64];
    __shared__ unsigned short Ps[128 * 64];

    const int tid  = threadIdx.x;
    const int w    = tid >> 6;          // wave 0..3
    const int lane = tid & 63;
    const int quad = lane >> 4;
    const int col  = lane & 15;
    const int q0   = blockIdx.x * 128;
    const int h    = blockIdx.y;
    const int b    = blockIdx.z;
    const int wq   = w * 32;            // 32 q-rows per wave

    const size_t headoff = (size_t)(b * 16 + h) * 2048 * 64;
    const unsigned short* Qh  = qbuf + headoff + (size_t)q0 * 64;
    const unsigned short* Kh  = kbuf + headoff;
    const unsigned short* Vth = vtbuf + headoff;

    // staging geometry: 2 chunks per thread per tensor per tile
    const int c0 = tid;
    const int c1 = 256 + tid;
    const int r0 = c0 >> 3, g0 = (c0 & 7) ^ (r0 & 7);
    const int r1 = c1 >> 3, g1 = (c1 & 7) ^ (r1 & 7);

#define STAGE(bufidx, kt) do {                                                  \
        ASYNC16(Kh + (size_t)((kt) * 64 + r0) * 64 + g0 * 8,                    \
                &Ks[bufidx][(size_t)(w * 64) * 8]);                             \
        ASYNC16(Kh + (size_t)((kt) * 64 + r1) * 64 + g1 * 8,                    \
                &Ks[bufidx][(size_t)(256 + w * 64) * 8]);                       \
        ASYNC16(Vth + (size_t)r0 * 2048 + (kt) * 64 + g0 * 8,                   \
                &Vts[bufidx][(size_t)(w * 64) * 8]);                            \
        ASYNC16(Vth + (size_t)r1 * 2048 + (kt) * 64 + g1 * 8,                   \
                &Vts[bufidx][(size_t)(256 + w * 64) * 8]);                      \
    } while (0)

    // Q fragments (A-layout: m=col, k=ks*32+quad*8+j), 2 m-tiles x 2 ks
    bf16x8 qf[2][2];
#pragma unroll
    for (int mt = 0; mt < 2; ++mt)
#pragma unroll
        for (int ks = 0; ks < 2; ++ks)
            qf[mt][ks] = *(const bf16x8*)
                &Qh[(size_t)(wq + mt * 16 + col) * 64 + ks * 32 + quad * 8];

    // posr row pointers (8 rows per lane: mt x r)
    const float* prq[2][4];
#pragma unroll
    for (int mt = 0; mt < 2; ++mt)
#pragma unroll
        for (int r = 0; r < 4; ++r)
            prq[mt][r] = posr +
                ((size_t)b * 2048 + (q0 + wq + mt * 16 + quad * 4 + r)) * 2048;
    const int* mrow = mask + (size_t)b * 2048;

    // stage tiles 0,1
    STAGE(0, 0);
    STAGE(1, 1);

    // posr/mask for tile 0
    float pr[2][4][4];
    int   mk[4];
#pragma unroll
    for (int mt = 0; mt < 2; ++mt)
#pragma unroll
        for (int r = 0; r < 4; ++r)
#pragma unroll
            for (int nt = 0; nt < 4; ++nt)
                pr[mt][r][nt] = prq[mt][r][nt * 16 + col];
#pragma unroll
    for (int nt = 0; nt < 4; ++nt) mk[nt] = mrow[nt * 16 + col];

    f32x4 sc[2][4];
    f32x4 O[2][4] = {};
    float lsum[2][4] = {{0.f, 0.f, 0.f, 0.f}, {0.f, 0.f, 0.f, 0.f}};

    __syncthreads();                    // tiles 0,1 staged (full drain, once)

    // QK(0) from buffer 0
#pragma unroll
    for (int mt = 0; mt < 2; ++mt)
#pragma unroll
        for (int nt = 0; nt < 4; ++nt) sc[mt][nt] = (f32x4){0.f, 0.f, 0.f, 0.f};
#pragma unroll
    for (int nt = 0; nt < 4; ++nt)
#pragma unroll
        for (int ks = 0; ks < 2; ++ks) {
            const bf16x8 bk = *(const bf16x8*)
                &Ks[0][(nt * 16 + col) * 64 + (((ks * 4 + quad) ^ (col & 7)) * 8)];
#pragma unroll
            for (int mt = 0; mt < 2; ++mt)
                sc[mt][nt] = MFMA16(qf[mt][ks], bk, sc[mt][nt]);
        }

    int bb = 0, b1 = 1, b2 = 2;
#pragma unroll 1
    for (int t = 0; t < 32; ++t) {
        // ---- softmax(t): p = exp2(sc + pr*log2e); truncate-pack; l exact ----
#pragma unroll
        for (int mt = 0; mt < 2; ++mt)
#pragma unroll
            for (int r = 0; r < 4; ++r) {
                const int rowW = wq + mt * 16 + quad * 4 + r;
                const int rsw  = rowW & 7;
#pragma unroll
                for (int nt = 0; nt < 4; ++nt) {
                    const float e = __builtin_amdgcn_exp2f(
                        fmaf(pr[mt][r][nt], LOG2E, sc[mt][nt][r]));
                    unsigned int u = __float_as_uint(e) & 0xffff0000u;
                    u = mk[nt] ? u : 0u;
                    lsum[mt][r] += __uint_as_float(u);
                    const int kk = nt * 16 + col;
                    Ps[rowW * 64 + (((kk >> 3) ^ rsw) * 8) + (kk & 7)] =
                        (unsigned short)(u >> 16);
                }
            }

        // barrier: publish Ps(t); stage(t+1) already covered by softmax's
        // wait on pr(t) (posr loads pinned after stages).  No vmcnt drain.
        __builtin_amdgcn_sched_barrier(0);
        asm volatile("s_waitcnt lgkmcnt(0)" ::: "memory");
        __builtin_amdgcn_s_barrier();
        __builtin_amdgcn_sched_barrier(0);

        // stage t+2 into b2 (its previous readers retired before last barrier)
        if (t < 30) STAGE(b2, t + 2);
        __builtin_amdgcn_sched_barrier(0);   // pin: stages BEFORE posr loads

        // posr/mask prefetch for t+1 (cover = PV + QK below)
        if (t < 31) {
            const int kn = (t + 1) * 64;
#pragma unroll
            for (int mt = 0; mt < 2; ++mt)
#pragma unroll
                for (int r = 0; r < 4; ++r)
#pragma unroll
                    for (int nt = 0; nt < 4; ++nt)
                        pr[mt][r][nt] = prq[mt][r][kn + nt * 16 + col];
#pragma unroll
            for (int nt = 0; nt < 4; ++nt) mk[nt] = mrow[kn + nt * 16 + col];
        }

        // ---- PV(t): O += P.V from buffer bb ----
#pragma unroll
        for (int ks = 0; ks < 2; ++ks) {
            bf16x8 pa[2];
#pragma unroll
            for (int mt = 0; mt < 2; ++mt)
                pa[mt] = *(const bf16x8*)
                    &Ps[(wq + mt * 16 + col) * 64 + (((ks * 4 + quad) ^ (col & 7)) * 8)];
#pragma unroll
            for (int nt = 0; nt < 4; ++nt) {
                const bf16x8 vb = *(const bf16x8*)
                    &Vts[bb][(nt * 16 + col) * 64 + (((ks * 4 + quad) ^ (col & 7)) * 8)];
#pragma unroll
                for (int mt = 0; mt < 2; ++mt)
                    O[mt][nt] = MFMA16(pa[mt], vb, O[mt][nt]);
            }
        }

        // ---- QK(t+1) from buffer b1 ----
        if (t < 31) {
#pragma unroll
            for (int mt = 0; mt < 2; ++mt)
#pragma unroll
                for (int nt = 0; nt < 4; ++nt)
                    sc[mt][nt] = (f32x4){0.f, 0.f, 0.f, 0.f};
#pragma unroll
            for (int nt = 0; nt < 4; ++nt)
#pragma unroll
                for (int ks = 0; ks < 2; ++ks) {
                    const bf16x8 bk = *(const bf16x8*)
                        &Ks[b1][(nt * 16 + col) * 64 + (((ks * 4 + quad) ^ (col & 7)) * 8)];
#pragma unroll
                    for (int mt = 0; mt < 2; ++mt)
                        sc[mt][nt] = MFMA16(qf[mt][ks], bk, sc[mt][nt]);
                }
        }
        const int tmp = bb; bb = b1; b1 = b2; b2 = tmp;
    }

    // ---- reduce l across the 16 cols (rows are wave-private) ----
#pragma unroll
    for (int mt = 0; mt < 2; ++mt)
#pragma unroll
        for (int r = 0; r < 4; ++r) {
#pragma unroll
            for (int o = 1; o < 16; o <<= 1)
                lsum[mt][r] += __shfl_xor(lsum[mt][r], o);
        }

    // ---- epilogue: ctx = O / l (bf16) ----
#pragma unroll
    for (int mt = 0; mt < 2; ++mt)
#pragma unroll
        for (int r = 0; r < 4; ++r) {
            const float inv = 1.f / lsum[mt][r];
            const int rowW = wq + mt * 16 + quad * 4 + r;
            const size_t rowoff =
                ((size_t)b * 2048 + (q0 + rowW)) * 1024 + h * 64;
#pragma unroll
            for (int nt = 0; nt < 4; ++nt)
                ctxb[rowoff + nt * 16 + col] = f2bf(O[mt][nt][r] * inv);
        }
#undef STAGE
}

// ---------------------------------------------------------------------------
extern "C" void kernel_launch(void* const* d_in, const int* in_sizes, int n_in,
                              void* d_out, int out_size, void* d_ws, size_t ws_size,
                              hipStream_t stream) {
    const float* query = (const float*)d_in[0];
    const float* key   = (const float*)d_in[1];
    const float* value = (const float*)d_in[2];
    const int*   mask  = (const int*)  d_in[3];
    const float* posr  = (const float*)d_in[4];
    const float* Wq    = (const float*)d_in[5];
    const float* bq    = (const float*)d_in[6];
    const float* Wk    = (const float*)d_in[7];
    const float* bk    = (const float*)d_in[8];
    const float* Wv    = (const float*)d_in[9];
    const float* bv    = (const float*)d_in[10];
    const float* Wo    = (const float*)d_in[11];
    const float* bo    = (const float*)d_in[12];
    float* out = (float*)d_out;

    unsigned short* ws0   = (unsigned short*)d_ws;
    const size_t IN = 4194304, WT = 1048576;
    unsigned short* qbuf  = ws0 + 4 * IN;
    unsigned short* kbuf  = ws0 + 5 * IN;
    unsigned short* vtbuf = ws0 + 6 * IN;
    unsigned short* ctxb  = ws0 + 7 * IN;
    const unsigned short* wob = ws0 + 3 * IN + 3 * WT;

    pack_all<<<dim3(512, 1, 7), 256, 0, stream>>>(query, key, value, Wq, Wk, Wv, Wo, ws0);

    gemm_qkv<<<dim3(16, 32, 3), 256, 0, stream>>>(ws0, bq, bk, bv, qbuf, kbuf, vtbuf);

    attn_mfma<<<dim3(16, 16, 2), 256, 0, stream>>>(qbuf, kbuf, vtbuf, posr, mask, ctxb);

    gemm_out<<<dim3(16, 32), 256, 0, stream>>>(ctxb, wob, bo, out);
}